// Round 2
// baseline (5233.657 us; speedup 1.0000x reference)
//
#include <hip/hip_runtime.h>

#define HD 512
#define VOC 10000
#define SL 32
#define BA 256
#define BH (BA*HD)

typedef __bf16 b16x8 __attribute__((ext_vector_type(8)));
typedef float f32x4 __attribute__((ext_vector_type(4)));

__device__ __forceinline__ ushort f2bf(float x) {
  unsigned u = __float_as_uint(x);
  u += 0x7fffu + ((u >> 16) & 1u);
  return (ushort)(u >> 16);
}

// ---------------- fp32 -> bf16 convert ----------------
__global__ __launch_bounds__(256) void cvt_k(const float* __restrict__ in,
                                             ushort* __restrict__ out, int n4) {
  int i = blockIdx.x * 256 + threadIdx.x;
  if (i < n4) {
    float4 v = ((const float4*)in)[i];
    ((ushort4*)out)[i] = make_ushort4(f2bf(v.x), f2bf(v.y), f2bf(v.z), f2bf(v.w));
  }
}

// ---------------- embedding gathers (rows = l*256+b) ----------------
__global__ __launch_bounds__(64) void gather_enc_k(const float* __restrict__ table,
                                                   const int* __restrict__ toks,
                                                   ushort* __restrict__ out) {
  int row = blockIdx.x;            // l*256 + b
  int l = row >> 8, b = row & 255;
  int tok = toks[b * SL + l];
  const float4* src = (const float4*)(table + (size_t)tok * HD);
  int t = threadIdx.x;
  float4 v0 = src[t * 2], v1 = src[t * 2 + 1];
  uint4 o;
  o.x = (unsigned)f2bf(v0.x) | ((unsigned)f2bf(v0.y) << 16);
  o.y = (unsigned)f2bf(v0.z) | ((unsigned)f2bf(v0.w) << 16);
  o.z = (unsigned)f2bf(v1.x) | ((unsigned)f2bf(v1.y) << 16);
  o.w = (unsigned)f2bf(v1.z) | ((unsigned)f2bf(v1.w) << 16);
  *(uint4*)(out + (size_t)row * HD + t * 8) = o;
}

__global__ __launch_bounds__(64) void gather_dec_k(const float* __restrict__ table,
                                                   const int* __restrict__ toks,
                                                   ushort* __restrict__ out) {
  int row = blockIdx.x;
  int l = row >> 8, b = row & 255;
  int tok = (l == 0) ? 1 : toks[b * SL + l - 1];
  const float4* src = (const float4*)(table + (size_t)tok * HD);
  int t = threadIdx.x;
  float4 v0 = src[t * 2], v1 = src[t * 2 + 1];
  uint4 o;
  o.x = (unsigned)f2bf(v0.x) | ((unsigned)f2bf(v0.y) << 16);
  o.y = (unsigned)f2bf(v0.z) | ((unsigned)f2bf(v0.w) << 16);
  o.z = (unsigned)f2bf(v1.x) | ((unsigned)f2bf(v1.y) << 16);
  o.w = (unsigned)f2bf(v1.z) | ((unsigned)f2bf(v1.w) << 16);
  *(uint4*)(out + (size_t)row * HD + t * 8) = o;
}

// ---------------- generic bf16 GEMM: C[m][n] = sum_k A[m][k]*W[n][k] ----------------
__global__ __launch_bounds__(256) void gemm_k(
    const ushort* __restrict__ A, const ushort* __restrict__ W,
    int N, int ldw,
    const float* __restrict__ bias, const float* __restrict__ addsrc,
    int relu, float* __restrict__ outf, int ldc, ushort* __restrict__ outbf) {
  __shared__ ushort lsA[4][64][8];
  __shared__ ushort lsB[4][64][8];
  int t = threadIdx.x;
  int lane = t & 63, w = t >> 6;
  int m0 = blockIdx.x * 64, n0 = blockIdx.y * 64;
  f32x4 acc[4] = {};
  int sr = t >> 2, g = t & 3;
  const ushort* Ap = A + (size_t)(m0 + sr) * HD + g * 8;
  int nr = n0 + sr; if (nr > N - 1) nr = N - 1;
  const ushort* Wp = W + (size_t)nr * ldw + g * 8;
  for (int ks = 0; ks < 16; ++ks) {
    *(uint4*)(&lsA[g][sr][0]) = *(const uint4*)(Ap + ks * 32);
    *(uint4*)(&lsB[g][sr][0]) = *(const uint4*)(Wp + ks * 32);
    __syncthreads();
    int gg = lane >> 4, r = lane & 15;
    b16x8 bf = *(const b16x8*)(&lsB[gg][w * 16 + r][0]);
#pragma unroll
    for (int mi = 0; mi < 4; ++mi) {
      b16x8 af = *(const b16x8*)(&lsA[gg][mi * 16 + r][0]);
      acc[mi] = __builtin_amdgcn_mfma_f32_16x16x32_bf16(af, bf, acc[mi], 0, 0, 0);
    }
    __syncthreads();
  }
  int gg = lane >> 4, cl = lane & 15;
  int col = n0 + w * 16 + cl;
  if (col >= N) return;
  float bv = bias ? bias[col] : 0.f;
#pragma unroll
  for (int mi = 0; mi < 4; ++mi) {
#pragma unroll
    for (int r = 0; r < 4; ++r) {
      int row = m0 + mi * 16 + gg * 4 + r;
      float v = acc[mi][r] + bv;
      if (addsrc) v += addsrc[(size_t)row * N + col];
      if (relu) v = fmaxf(v, 0.f);
      if (outf) outf[(size_t)row * ldc + col] = v;
      if (outbf) outbf[(size_t)row * N + col] = f2bf(v);
    }
  }
}

// ---------------- persistent recurrence kernel ----------------
// 256 blocks x 256 threads. rg = bid>>5 (8 groups x 32 batch rows), sl = bid&31.
// All data flow is row-group-local -> rg-local spin barriers (32 blocks each).

struct CoopArgs {
  const ushort* enc_emb_bf;
  ushort* enc_outs_bf;       // [SL][BA][HD] bf16 (encoder h per step)
  float* Hcarry;             // [BA][HD] f32 running hidden (enc then dec)
  ushort* H2_bf;             // [SL][BA][HD] bf16 decoder hidden outputs
  ushort* x_bf;              // [BA][HD] comb output
  ushort* applied_bf;        // [BA][HD] attention applied
  const ushort* enc_wih; const ushort* enc_whh;
  const float* enc_b_ih; const float* enc_b_hh;
  const ushort* dec_wih; const ushort* dec_whh;
  const float* dec_b_ih; const float* dec_b_hh;
  const ushort* attn_w_bf;   // [32][1024] bf16 (right half used)
  const float* attn_pre;     // [SL*BA][32]
  const ushort* comb_w_bf;   // [512][1024] bf16 (right half used)
  const float* comb_pre;     // [SL*BA][512]
  const ushort* zero_bf;
  const float* zero_f32;
  unsigned int* ctr;         // 8 counters, stride 64 uints
};

__device__ __forceinline__ void gru_phase(
    int r0, int sl, int lane, int w,
    const ushort* __restrict__ x_src, const ushort* __restrict__ h_src,
    const ushort* __restrict__ Wih, const ushort* __restrict__ Whh,
    const float* __restrict__ b_ih, const float* __restrict__ b_hh,
    const float* __restrict__ hp_src, float* __restrict__ hf_dst,
    ushort* __restrict__ hbf_dst, float (*red)[6][64][4]) {
  int mf = w & 1, kh = w >> 1;
  int lr = lane & 15, gg = lane >> 4;
  int row_a = r0 + mf * 16 + lr;
  int jrow = sl * 16 + lr;
  const ushort* xr = x_src + (size_t)row_a * HD + kh * 256 + gg * 8;
  const ushort* hr = h_src + (size_t)row_a * HD + kh * 256 + gg * 8;
  const ushort* wi = Wih + (size_t)jrow * HD + kh * 256 + gg * 8;
  const ushort* wh = Whh + (size_t)jrow * HD + kh * 256 + gg * 8;
  f32x4 acc[6] = {};
#pragma unroll
  for (int ks = 0; ks < 8; ++ks) {
    b16x8 ax = *(const b16x8*)(xr + ks * 32);
    b16x8 ah = *(const b16x8*)(hr + ks * 32);
#pragma unroll
    for (int g3 = 0; g3 < 3; ++g3) {
      b16x8 bi = *(const b16x8*)(wi + (size_t)g3 * 512 * HD + ks * 32);
      b16x8 bh = *(const b16x8*)(wh + (size_t)g3 * 512 * HD + ks * 32);
      acc[g3] = __builtin_amdgcn_mfma_f32_16x16x32_bf16(ax, bi, acc[g3], 0, 0, 0);
      acc[3 + g3] = __builtin_amdgcn_mfma_f32_16x16x32_bf16(ah, bh, acc[3 + g3], 0, 0, 0);
    }
  }
  if (kh == 1) {
#pragma unroll
    for (int s = 0; s < 6; ++s) *(f32x4*)&red[mf][s][lane][0] = acc[s];
  }
  __syncthreads();
  if (kh == 0) {
    int j = sl * 16 + lr;
#pragma unroll
    for (int s = 0; s < 6; ++s) acc[s] += *(const f32x4*)&red[mf][s][lane][0];
    float bir = b_ih[j], biz = b_ih[512 + j], bin_ = b_ih[1024 + j];
    float bhr = b_hh[j], bhz = b_hh[512 + j], bhn = b_hh[1024 + j];
#pragma unroll
    for (int ri = 0; ri < 4; ++ri) {
      int row = r0 + mf * 16 + gg * 4 + ri;
      float ir = acc[0][ri] + bir, iz = acc[1][ri] + biz, inn = acc[2][ri] + bin_;
      float hr2 = acc[3][ri] + bhr, hz = acc[4][ri] + bhz, hn = acc[5][ri] + bhn;
      float rr = 1.f / (1.f + expf(-(ir + hr2)));
      float zz = 1.f / (1.f + expf(-(iz + hz)));
      float nn = tanhf(inn + rr * hn);
      float hp = hp_src[(size_t)row * HD + j];
      float h2 = (1.f - zz) * nn + zz * hp;
      hf_dst[(size_t)row * HD + j] = h2;
      hbf_dst[(size_t)row * HD + j] = f2bf(h2);
    }
  }
}

__device__ __forceinline__ void comb_phase(
    int r0, int sl, int lane, int w, int l,
    const ushort* __restrict__ applied, const ushort* __restrict__ comb_w_bf,
    const float* __restrict__ comb_pre, ushort* __restrict__ x_bf,
    float (*red)[6][64][4]) {
  int mf = w & 1, kh = w >> 1;
  int lr = lane & 15, gg = lane >> 4;
  int row_a = r0 + mf * 16 + lr;
  int nrow = sl * 16 + lr;
  const ushort* ar = applied + (size_t)row_a * HD + kh * 256 + gg * 8;
  const ushort* wr = comb_w_bf + (size_t)nrow * 1024 + 512 + kh * 256 + gg * 8;
  f32x4 acc = {};
#pragma unroll
  for (int ks = 0; ks < 8; ++ks) {
    b16x8 av = *(const b16x8*)(ar + ks * 32);
    b16x8 bv = *(const b16x8*)(wr + ks * 32);
    acc = __builtin_amdgcn_mfma_f32_16x16x32_bf16(av, bv, acc, 0, 0, 0);
  }
  if (kh == 1) *(f32x4*)&red[mf][0][lane][0] = acc;
  __syncthreads();
  if (kh == 0) {
    acc += *(const f32x4*)&red[mf][0][lane][0];
    int n = sl * 16 + lr;
#pragma unroll
    for (int ri = 0; ri < 4; ++ri) {
      int row = r0 + mf * 16 + gg * 4 + ri;
      float v = acc[ri] + comb_pre[((size_t)l * BA + row) * HD + n];
      v = fmaxf(v, 0.f);
      x_bf[(size_t)row * HD + n] = f2bf(v);
    }
  }
}

__device__ __forceinline__ void attn_phase(
    int r0, int sl, int lane, int w, int t, int l,
    const ushort* __restrict__ h_bf, const ushort* __restrict__ attn_w_bf,
    const float* __restrict__ attn_pre, const ushort* __restrict__ enc_bf,
    ushort* __restrict__ applied,
    float (*sS)[32][33], float (*sAW)[33]) {
  int mf = w & 1, kh = w >> 1;
  int lr = lane & 15, gg = lane >> 4;
  int row_a = r0 + mf * 16 + lr;
  const ushort* hr = h_bf + (size_t)row_a * HD + kh * 256 + gg * 8;
  const ushort* w0 = attn_w_bf + (size_t)lr * 1024 + 512 + kh * 256 + gg * 8;
  const ushort* w1 = attn_w_bf + (size_t)(16 + lr) * 1024 + 512 + kh * 256 + gg * 8;
  f32x4 a0 = {}, a1 = {};
#pragma unroll
  for (int ks = 0; ks < 8; ++ks) {
    b16x8 ah = *(const b16x8*)(hr + ks * 32);
    b16x8 b0 = *(const b16x8*)(w0 + ks * 32);
    b16x8 b1 = *(const b16x8*)(w1 + ks * 32);
    a0 = __builtin_amdgcn_mfma_f32_16x16x32_bf16(ah, b0, a0, 0, 0, 0);
    a1 = __builtin_amdgcn_mfma_f32_16x16x32_bf16(ah, b1, a1, 0, 0, 0);
  }
#pragma unroll
  for (int ri = 0; ri < 4; ++ri) {
    sS[kh][mf * 16 + gg * 4 + ri][lr] = a0[ri];
    sS[kh][mf * 16 + gg * 4 + ri][16 + lr] = a1[ri];
  }
  __syncthreads();
  // softmax over 32 logits per row; t -> (r = t>>3, q = t&7 owns 4 logits)
  int r = t >> 3, q = t & 7;
  float4 pre = *(const float4*)(attn_pre + ((size_t)l * BA + r0 + r) * 32 + q * 4);
  float v0 = sS[0][r][q * 4 + 0] + sS[1][r][q * 4 + 0] + pre.x;
  float v1 = sS[0][r][q * 4 + 1] + sS[1][r][q * 4 + 1] + pre.y;
  float v2 = sS[0][r][q * 4 + 2] + sS[1][r][q * 4 + 2] + pre.z;
  float v3 = sS[0][r][q * 4 + 3] + sS[1][r][q * 4 + 3] + pre.w;
  float mx = fmaxf(fmaxf(v0, v1), fmaxf(v2, v3));
  for (int o = 1; o < 8; o <<= 1) mx = fmaxf(mx, __shfl_xor(mx, o, 64));
  float e0 = expf(v0 - mx), e1 = expf(v1 - mx), e2 = expf(v2 - mx), e3 = expf(v3 - mx);
  float s = e0 + e1 + e2 + e3;
  for (int o = 1; o < 8; o <<= 1) s += __shfl_xor(s, o, 64);
  float inv = 1.f / s;
  sAW[r][q * 4 + 0] = e0 * inv; sAW[r][q * 4 + 1] = e1 * inv;
  sAW[r][q * 4 + 2] = e2 * inv; sAW[r][q * 4 + 3] = e3 * inv;
  __syncthreads();
  // apply d-slice: d0 = sl*16, each thread 2 d's
  int d0 = sl * 16;
  int rr = t >> 3, dp = t & 7;
  int d = d0 + dp * 2;
  float f0 = 0.f, f1 = 0.f;
#pragma unroll 8
  for (int ll = 0; ll < 32; ++ll) {
    float aw = sAW[rr][ll];
    unsigned u = *(const unsigned*)(enc_bf + ((size_t)ll * BA + r0 + rr) * HD + d);
    f0 += aw * __uint_as_float(u << 16);
    f1 += aw * __uint_as_float(u & 0xffff0000u);
  }
  unsigned ov = (unsigned)f2bf(f0) | ((unsigned)f2bf(f1) << 16);
  *(unsigned*)(applied + (size_t)(r0 + rr) * HD + d) = ov;
}

__global__ __launch_bounds__(256) void coop_k(CoopArgs a) {
  __shared__ float red[2][6][64][4];
  __shared__ float sS[2][32][33];
  __shared__ float sAW[32][33];
  int bid = blockIdx.x;
  int rg = bid >> 5, sl = bid & 31;
  int t = threadIdx.x, lane = t & 63, w = t >> 6;
  int r0 = rg * 32;
  unsigned int* ctr = a.ctr + rg * 64;
  int sync_idx = 0;

  auto gsync = [&]() {
    ++sync_idx;
    __syncthreads();
    if (t == 0) {
      __threadfence();
      __hip_atomic_fetch_add(ctr, 1u, __ATOMIC_RELEASE, __HIP_MEMORY_SCOPE_AGENT);
      while (__hip_atomic_load(ctr, __ATOMIC_ACQUIRE, __HIP_MEMORY_SCOPE_AGENT) <
             (unsigned int)(32 * sync_idx))
        __builtin_amdgcn_s_sleep(2);
    }
    __syncthreads();
    __threadfence();
  };

  // ---- encoder: 32 steps ----
  for (int l = 0; l < SL; ++l) {
    const ushort* h_src = l ? a.enc_outs_bf + (size_t)(l - 1) * BH : a.zero_bf;
    const float* hp = l ? a.Hcarry : a.zero_f32;
    gru_phase(r0, sl, lane, w, a.enc_emb_bf + (size_t)l * BH, h_src,
              a.enc_wih, a.enc_whh, a.enc_b_ih, a.enc_b_hh,
              hp, a.Hcarry, a.enc_outs_bf + (size_t)l * BH, red);
    gsync();
  }
  // ---- decoder: 32 steps x 3 phases ----
  for (int l = 0; l < SL; ++l) {
    const ushort* h_bf = l ? a.H2_bf + (size_t)(l - 1) * BH
                           : a.enc_outs_bf + (size_t)31 * BH;
    attn_phase(r0, sl, lane, w, t, l, h_bf, a.attn_w_bf, a.attn_pre,
               a.enc_outs_bf, a.applied_bf, sS, sAW);
    gsync();
    comb_phase(r0, sl, lane, w, l, a.applied_bf, a.comb_w_bf, a.comb_pre,
               a.x_bf, red);
    gsync();
    gru_phase(r0, sl, lane, w, a.x_bf, h_bf, a.dec_wih, a.dec_whh,
              a.dec_b_ih, a.dec_b_hh, a.Hcarry, a.Hcarry,
              a.H2_bf + (size_t)l * BH, red);
    gsync();
  }
}

// ---------------- log-softmax: pass 1 (per-row logsumexp) ----------------
__global__ __launch_bounds__(256) void lse_k(const float* __restrict__ logits,
                                             float* __restrict__ z) {
  __shared__ float red[4];
  int row = blockIdx.x, t = threadIdx.x;
  const float4* p = (const float4*)(logits + (size_t)row * VOC);
  float m = -1e30f;
  for (int i = t; i < 2500; i += 256) {
    float4 v = p[i];
    m = fmaxf(fmaxf(m, fmaxf(v.x, v.y)), fmaxf(v.z, v.w));
  }
  for (int o = 32; o; o >>= 1) m = fmaxf(m, __shfl_xor(m, o, 64));
  if ((t & 63) == 0) red[t >> 6] = m;
  __syncthreads();
  m = fmaxf(fmaxf(red[0], red[1]), fmaxf(red[2], red[3]));
  __syncthreads();
  float s = 0.f;
  for (int i = t; i < 2500; i += 256) {
    float4 v = p[i];
    s += expf(v.x - m) + expf(v.y - m) + expf(v.z - m) + expf(v.w - m);
  }
  for (int o = 32; o; o >>= 1) s += __shfl_xor(s, o, 64);
  if ((t & 63) == 0) red[t >> 6] = s;
  __syncthreads();
  if (t == 0) z[row] = m + logf(red[0] + red[1] + red[2] + red[3]);
}

// ---------------- log-softmax: pass 2 (subtract) ----------------
__global__ __launch_bounds__(256) void sub_k(float* __restrict__ logits,
                                             const float* __restrict__ z) {
  int row = blockIdx.y;
  int i = blockIdx.x * 256 + threadIdx.x;
  if (i < 2500) {
    float4* p = (float4*)(logits + (size_t)row * VOC);
    float zv = z[row];
    float4 v = p[i];
    v.x -= zv; v.y -= zv; v.z -= zv; v.w -= zv;
    p[i] = v;
  }
}

extern "C" void kernel_launch(void* const* d_in, const int* in_sizes, int n_in,
                              void* d_out, int out_size, void* d_ws, size_t ws_size,
                              hipStream_t stream) {
  (void)in_sizes; (void)n_in; (void)out_size; (void)ws_size;
  const int* in_tok = (const int*)d_in[0];
  const int* tgt_tok = (const int*)d_in[1];
  const float* enc_embed = (const float*)d_in[2];
  const float* enc_w_ih = (const float*)d_in[3];
  const float* enc_w_hh = (const float*)d_in[4];
  const float* enc_b_ih = (const float*)d_in[5];
  const float* enc_b_hh = (const float*)d_in[6];
  const float* dec_embed = (const float*)d_in[7];
  const float* attn_w = (const float*)d_in[8];
  const float* attn_b = (const float*)d_in[9];
  const float* comb_w = (const float*)d_in[10];
  const float* comb_b = (const float*)d_in[11];
  const float* dec_w_ih = (const float*)d_in[12];
  const float* dec_w_hh = (const float*)d_in[13];
  const float* dec_b_ih = (const float*)d_in[14];
  const float* dec_b_hh = (const float*)d_in[15];
  const float* out_w = (const float*)d_in[16];
  const float* out_b = (const float*)d_in[17];
  float* out = (float*)d_out;

  char* ws = (char*)d_ws;
  size_t off = 0;
  auto carve = [&](size_t bytes) {
    void* p = ws + off;
    off += (bytes + 255) & ~(size_t)255;
    return p;
  };
  ushort* enc_wih_bf = (ushort*)carve(1536 * 512 * 2);
  ushort* enc_whh_bf = (ushort*)carve(1536 * 512 * 2);
  ushort* dec_wih_bf = (ushort*)carve(1536 * 512 * 2);
  ushort* dec_whh_bf = (ushort*)carve(1536 * 512 * 2);
  ushort* comb_w_bf  = (ushort*)carve(512 * 1024 * 2);
  ushort* attn_w_bf  = (ushort*)carve(32 * 1024 * 2);
  ushort* out_w_bf   = (ushort*)carve((size_t)VOC * HD * 2);
  ushort* enc_emb_bf = (ushort*)carve((size_t)SL * BA * HD * 2);
  ushort* dec_emb_bf = (ushort*)carve((size_t)SL * BA * HD * 2);
  float* attn_pre    = (float*)carve((size_t)SL * BA * 32 * 4);
  float* comb_pre    = (float*)carve((size_t)SL * BA * HD * 4);
  ushort* enc_outs_bf= (ushort*)carve((size_t)SL * BA * HD * 2);
  ushort* H2_bf      = (ushort*)carve((size_t)SL * BA * HD * 2);
  float* Hcarry      = (float*)carve(BH * 4);
  ushort* zero_bf    = (ushort*)carve(BH * 2);
  float* zero_f32    = (float*)carve(BH * 4);
  ushort* applied_bf = (ushort*)carve(BH * 2);
  ushort* x_bf       = (ushort*)carve(BH * 2);
  float* zbuf        = (float*)carve(SL * BA * 4);
  unsigned int* ctr  = (unsigned int*)carve(8 * 64 * 4);

  // ---- setup: converts, gathers, zero buffers ----
  cvt_k<<<768, 256, 0, stream>>>(enc_w_ih, enc_wih_bf, 1536 * 512 / 4);
  cvt_k<<<768, 256, 0, stream>>>(enc_w_hh, enc_whh_bf, 1536 * 512 / 4);
  cvt_k<<<768, 256, 0, stream>>>(dec_w_ih, dec_wih_bf, 1536 * 512 / 4);
  cvt_k<<<768, 256, 0, stream>>>(dec_w_hh, dec_whh_bf, 1536 * 512 / 4);
  cvt_k<<<512, 256, 0, stream>>>(comb_w, comb_w_bf, 512 * 1024 / 4);
  cvt_k<<<32, 256, 0, stream>>>(attn_w, attn_w_bf, 32 * 1024 / 4);
  cvt_k<<<5000, 256, 0, stream>>>(out_w, out_w_bf, VOC * HD / 4);
  gather_enc_k<<<SL * BA, 64, 0, stream>>>(enc_embed, in_tok, enc_emb_bf);
  gather_dec_k<<<SL * BA, 64, 0, stream>>>(dec_embed, tgt_tok, dec_emb_bf);
  hipMemsetAsync(zero_bf, 0, BH * 2, stream);
  hipMemsetAsync(zero_f32, 0, BH * 4, stream);
  hipMemsetAsync(ctr, 0, 8 * 64 * 4, stream);

  // ---- decoder embedding-dependent precomputes ----
  gemm_k<<<dim3(128, 1), 256, 0, stream>>>(dec_emb_bf, attn_w_bf, 32, 1024,
                                           attn_b, nullptr, 0, attn_pre, 32, nullptr);
  gemm_k<<<dim3(128, 8), 256, 0, stream>>>(dec_emb_bf, comb_w_bf, 512, 1024,
                                           comb_b, nullptr, 0, comb_pre, 512, nullptr);

  // ---- persistent recurrence ----
  CoopArgs ca;
  ca.enc_emb_bf = enc_emb_bf;
  ca.enc_outs_bf = enc_outs_bf;
  ca.Hcarry = Hcarry;
  ca.H2_bf = H2_bf;
  ca.x_bf = x_bf;
  ca.applied_bf = applied_bf;
  ca.enc_wih = enc_wih_bf; ca.enc_whh = enc_whh_bf;
  ca.enc_b_ih = enc_b_ih; ca.enc_b_hh = enc_b_hh;
  ca.dec_wih = dec_wih_bf; ca.dec_whh = dec_whh_bf;
  ca.dec_b_ih = dec_b_ih; ca.dec_b_hh = dec_b_hh;
  ca.attn_w_bf = attn_w_bf;
  ca.attn_pre = attn_pre;
  ca.comb_w_bf = comb_w_bf;
  ca.comb_pre = comb_pre;
  ca.zero_bf = zero_bf;
  ca.zero_f32 = zero_f32;
  ca.ctr = ctr;
  coop_k<<<256, 256, 0, stream>>>(ca);

  // ---- output projection + log_softmax ----
  gemm_k<<<dim3(128, 157), 256, 0, stream>>>(H2_bf, out_w_bf, VOC, HD,
                                             out_b, nullptr, 0, out, VOC, nullptr);
  lse_k<<<SL * BA, 256, 0, stream>>>(out, zbuf);
  sub_k<<<dim3(10, SL * BA), 256, 0, stream>>>(out, zbuf);
}

// Round 3
// 2255.492 us; speedup vs baseline: 2.3204x; 2.3204x over previous
//
#include <hip/hip_runtime.h>

#define HD 512
#define VOC 10000
#define SL 32
#define BA 256
#define BH (BA*HD)

typedef __bf16 b16x8 __attribute__((ext_vector_type(8)));
typedef float f32x4 __attribute__((ext_vector_type(4)));

__device__ __forceinline__ ushort f2bf(float x) {
  unsigned u = __float_as_uint(x);
  u += 0x7fffu + ((u >> 16) & 1u);
  return (ushort)(u >> 16);
}

// ---- LLC-coherent (cache-bypassing) accessors: no L2 invalidation needed ----
__device__ __forceinline__ unsigned long long ld_sc1(const ushort* p) {
  return __hip_atomic_load((const unsigned long long*)p, __ATOMIC_RELAXED,
                           __HIP_MEMORY_SCOPE_AGENT);
}
__device__ __forceinline__ void st_sc1(ushort* p, unsigned long long v) {
  __hip_atomic_store((unsigned long long*)p, v, __ATOMIC_RELAXED,
                     __HIP_MEMORY_SCOPE_AGENT);
}
__device__ __forceinline__ b16x8 ldfrag_sc1(const ushort* p) {
  union { unsigned long long q[2]; b16x8 v; } u;
  u.q[0] = ld_sc1(p);
  u.q[1] = ld_sc1(p + 4);
  return u.v;
}

// ---------------- fp32 -> bf16 convert ----------------
__global__ __launch_bounds__(256) void cvt_k(const float* __restrict__ in,
                                             ushort* __restrict__ out, int n4) {
  int i = blockIdx.x * 256 + threadIdx.x;
  if (i < n4) {
    float4 v = ((const float4*)in)[i];
    ((ushort4*)out)[i] = make_ushort4(f2bf(v.x), f2bf(v.y), f2bf(v.z), f2bf(v.w));
  }
}

// ---------------- embedding gathers (rows = l*256+b) ----------------
__global__ __launch_bounds__(64) void gather_enc_k(const float* __restrict__ table,
                                                   const int* __restrict__ toks,
                                                   ushort* __restrict__ out) {
  int row = blockIdx.x;            // l*256 + b
  int l = row >> 8, b = row & 255;
  int tok = toks[b * SL + l];
  const float4* src = (const float4*)(table + (size_t)tok * HD);
  int t = threadIdx.x;
  float4 v0 = src[t * 2], v1 = src[t * 2 + 1];
  uint4 o;
  o.x = (unsigned)f2bf(v0.x) | ((unsigned)f2bf(v0.y) << 16);
  o.y = (unsigned)f2bf(v0.z) | ((unsigned)f2bf(v0.w) << 16);
  o.z = (unsigned)f2bf(v1.x) | ((unsigned)f2bf(v1.y) << 16);
  o.w = (unsigned)f2bf(v1.z) | ((unsigned)f2bf(v1.w) << 16);
  *(uint4*)(out + (size_t)row * HD + t * 8) = o;
}

__global__ __launch_bounds__(64) void gather_dec_k(const float* __restrict__ table,
                                                   const int* __restrict__ toks,
                                                   ushort* __restrict__ out) {
  int row = blockIdx.x;
  int l = row >> 8, b = row & 255;
  int tok = (l == 0) ? 1 : toks[b * SL + l - 1];
  const float4* src = (const float4*)(table + (size_t)tok * HD);
  int t = threadIdx.x;
  float4 v0 = src[t * 2], v1 = src[t * 2 + 1];
  uint4 o;
  o.x = (unsigned)f2bf(v0.x) | ((unsigned)f2bf(v0.y) << 16);
  o.y = (unsigned)f2bf(v0.z) | ((unsigned)f2bf(v0.w) << 16);
  o.z = (unsigned)f2bf(v1.x) | ((unsigned)f2bf(v1.y) << 16);
  o.w = (unsigned)f2bf(v1.z) | ((unsigned)f2bf(v1.w) << 16);
  *(uint4*)(out + (size_t)row * HD + t * 8) = o;
}

// ---------------- generic bf16 GEMM: C[m][n] = sum_k A[m][k]*W[n][k] ----------------
__global__ __launch_bounds__(256) void gemm_k(
    const ushort* __restrict__ A, const ushort* __restrict__ W,
    int N, int ldw,
    const float* __restrict__ bias, const float* __restrict__ addsrc,
    int relu, float* __restrict__ outf, int ldc, ushort* __restrict__ outbf) {
  __shared__ ushort lsA[4][64][8];
  __shared__ ushort lsB[4][64][8];
  int t = threadIdx.x;
  int lane = t & 63, w = t >> 6;
  int m0 = blockIdx.x * 64, n0 = blockIdx.y * 64;
  f32x4 acc[4] = {};
  int sr = t >> 2, g = t & 3;
  const ushort* Ap = A + (size_t)(m0 + sr) * HD + g * 8;
  int nr = n0 + sr; if (nr > N - 1) nr = N - 1;
  const ushort* Wp = W + (size_t)nr * ldw + g * 8;
  for (int ks = 0; ks < 16; ++ks) {
    *(uint4*)(&lsA[g][sr][0]) = *(const uint4*)(Ap + ks * 32);
    *(uint4*)(&lsB[g][sr][0]) = *(const uint4*)(Wp + ks * 32);
    __syncthreads();
    int gg = lane >> 4, r = lane & 15;
    b16x8 bf = *(const b16x8*)(&lsB[gg][w * 16 + r][0]);
#pragma unroll
    for (int mi = 0; mi < 4; ++mi) {
      b16x8 af = *(const b16x8*)(&lsA[gg][mi * 16 + r][0]);
      acc[mi] = __builtin_amdgcn_mfma_f32_16x16x32_bf16(af, bf, acc[mi], 0, 0, 0);
    }
    __syncthreads();
  }
  int gg = lane >> 4, cl = lane & 15;
  int col = n0 + w * 16 + cl;
  if (col >= N) return;
  float bv = bias ? bias[col] : 0.f;
#pragma unroll
  for (int mi = 0; mi < 4; ++mi) {
#pragma unroll
    for (int r = 0; r < 4; ++r) {
      int row = m0 + mi * 16 + gg * 4 + r;
      float v = acc[mi][r] + bv;
      if (addsrc) v += addsrc[(size_t)row * N + col];
      if (relu) v = fmaxf(v, 0.f);
      if (outf) outf[(size_t)row * ldc + col] = v;
      if (outbf) outbf[(size_t)row * N + col] = f2bf(v);
    }
  }
}

// ---------------- persistent recurrence kernel ----------------
// 256 blocks x 256 threads. rg = bid>>5 (8 groups x 32 batch rows), sl = bid&31.
// Data flow rg-local. Weights/embeddings/precomputes: plain cached loads (L2
// stays hot — no acquire fences anywhere). Dynamic activations: sc1 atomic
// loads/stores straight to/from LLC.

struct CoopArgs {
  const ushort* enc_emb_bf;
  ushort* enc_outs_bf;       // [SL][BA][HD]
  ushort* H2_bf;             // [SL][BA][HD]
  ushort* x_bf;              // [BA][HD]
  ushort* applied_bf;        // [BA][HD]
  const ushort* enc_wih; const ushort* enc_whh;
  const float* enc_b_ih; const float* enc_b_hh;
  const ushort* dec_wih; const ushort* dec_whh;
  const float* dec_b_ih; const float* dec_b_hh;
  const ushort* attn_w_bf;   // [32][1024] (right half used)
  const float* attn_pre;     // [SL*BA][32]
  const ushort* comb_w_bf;   // [512][1024] (right half used)
  const float* comb_pre;     // [SL*BA][512]
  unsigned int* ctr;         // 8 counters, stride 64 uints
};

template <bool XFRESH>
__device__ __forceinline__ void gru_phase(
    int r0, int sl, int lane, int w, int t,
    const ushort* __restrict__ x_src, const ushort* __restrict__ h_src,
    const ushort* __restrict__ Wih, const ushort* __restrict__ Whh,
    const float* __restrict__ b_ih, const float* __restrict__ b_hh,
    float* hp, ushort* __restrict__ hbf_dst,
    float (*red)[6][64][4], ushort (*stile)[16]) {
  int mf = w & 1, kh = w >> 1;
  int lr = lane & 15, gg = lane >> 4;
  int row_a = r0 + mf * 16 + lr;
  int jrow = sl * 16 + lr;
  const ushort* xr = x_src + (size_t)row_a * HD + kh * 256 + gg * 8;
  const ushort* hr = h_src ? h_src + (size_t)row_a * HD + kh * 256 + gg * 8 : nullptr;
  const ushort* wi = Wih + (size_t)jrow * HD + kh * 256 + gg * 8;
  const ushort* wh = Whh + (size_t)jrow * HD + kh * 256 + gg * 8;
  f32x4 acc[6] = {};
#pragma unroll
  for (int ks = 0; ks < 8; ++ks) {
    b16x8 ax = XFRESH ? ldfrag_sc1(xr + ks * 32) : *(const b16x8*)(xr + ks * 32);
    b16x8 ah = {};
    if (hr) ah = ldfrag_sc1(hr + ks * 32);
#pragma unroll
    for (int g3 = 0; g3 < 3; ++g3) {
      b16x8 bi = *(const b16x8*)(wi + (size_t)g3 * 512 * HD + ks * 32);
      b16x8 bh = *(const b16x8*)(wh + (size_t)g3 * 512 * HD + ks * 32);
      acc[g3] = __builtin_amdgcn_mfma_f32_16x16x32_bf16(ax, bi, acc[g3], 0, 0, 0);
      acc[3 + g3] = __builtin_amdgcn_mfma_f32_16x16x32_bf16(ah, bh, acc[3 + g3], 0, 0, 0);
    }
  }
  if (kh == 1) {
#pragma unroll
    for (int s = 0; s < 6; ++s) *(f32x4*)&red[mf][s][lane][0] = acc[s];
  }
  __syncthreads();
  if (kh == 0) {
    int j = sl * 16 + lr;
#pragma unroll
    for (int s = 0; s < 6; ++s) acc[s] += *(const f32x4*)&red[mf][s][lane][0];
    float bir = b_ih[j], biz = b_ih[512 + j], bin_ = b_ih[1024 + j];
    float bhr = b_hh[j], bhz = b_hh[512 + j], bhn = b_hh[1024 + j];
#pragma unroll
    for (int ri = 0; ri < 4; ++ri) {
      float ir = acc[0][ri] + bir, iz = acc[1][ri] + biz, inn = acc[2][ri] + bin_;
      float hr2 = acc[3][ri] + bhr, hz = acc[4][ri] + bhz, hn = acc[5][ri] + bhn;
      float rr = 1.f / (1.f + expf(-(ir + hr2)));
      float zz = 1.f / (1.f + expf(-(iz + hz)));
      float nn = tanhf(inn + rr * hn);
      float h2 = (1.f - zz) * nn + zz * hp[ri];
      hp[ri] = h2;
      stile[mf * 16 + gg * 4 + ri][lr] = f2bf(h2);
    }
  }
  __syncthreads();
  if (t < 128) {
    int row = t >> 2, c = t & 3;
    st_sc1(hbf_dst + (size_t)(r0 + row) * HD + sl * 16 + c * 4,
           *(const unsigned long long*)&stile[row][c * 4]);
  }
}

__device__ __forceinline__ void comb_phase(
    int r0, int sl, int lane, int w, int t, int l,
    const ushort* __restrict__ applied, const ushort* __restrict__ comb_w_bf,
    const float* __restrict__ comb_pre, ushort* __restrict__ x_bf,
    float (*red)[6][64][4], ushort (*stile)[16]) {
  int mf = w & 1, kh = w >> 1;
  int lr = lane & 15, gg = lane >> 4;
  int row_a = r0 + mf * 16 + lr;
  int nrow = sl * 16 + lr;
  const ushort* ar = applied + (size_t)row_a * HD + kh * 256 + gg * 8;
  const ushort* wr = comb_w_bf + (size_t)nrow * 1024 + 512 + kh * 256 + gg * 8;
  f32x4 acc = {};
#pragma unroll
  for (int ks = 0; ks < 8; ++ks) {
    b16x8 av = ldfrag_sc1(ar + ks * 32);
    b16x8 bv = *(const b16x8*)(wr + ks * 32);
    acc = __builtin_amdgcn_mfma_f32_16x16x32_bf16(av, bv, acc, 0, 0, 0);
  }
  if (kh == 1) *(f32x4*)&red[mf][0][lane][0] = acc;
  __syncthreads();
  if (kh == 0) {
    acc += *(const f32x4*)&red[mf][0][lane][0];
    int n = sl * 16 + lr;
#pragma unroll
    for (int ri = 0; ri < 4; ++ri) {
      int row = r0 + mf * 16 + gg * 4 + ri;
      float v = acc[ri] + comb_pre[((size_t)l * BA + row) * HD + n];
      v = fmaxf(v, 0.f);
      stile[mf * 16 + gg * 4 + ri][lr] = f2bf(v);
    }
  }
  __syncthreads();
  if (t < 128) {
    int row = t >> 2, c = t & 3;
    st_sc1(x_bf + (size_t)(r0 + row) * HD + sl * 16 + c * 4,
           *(const unsigned long long*)&stile[row][c * 4]);
  }
}

__device__ __forceinline__ void attn_phase(
    int r0, int sl, int lane, int w, int t, int l,
    const ushort* __restrict__ h_bf, const ushort* __restrict__ attn_w_bf,
    const float* __restrict__ attn_pre, const ushort* __restrict__ enc_bf,
    ushort* __restrict__ applied,
    float (*sS)[32][33], float (*sAW)[33], ushort (*stile)[16]) {
  int mf = w & 1, kh = w >> 1;
  int lr = lane & 15, gg = lane >> 4;
  int row_a = r0 + mf * 16 + lr;
  const ushort* hr = h_bf + (size_t)row_a * HD + kh * 256 + gg * 8;
  const ushort* w0 = attn_w_bf + (size_t)lr * 1024 + 512 + kh * 256 + gg * 8;
  const ushort* w1 = attn_w_bf + (size_t)(16 + lr) * 1024 + 512 + kh * 256 + gg * 8;
  f32x4 a0 = {}, a1 = {};
#pragma unroll
  for (int ks = 0; ks < 8; ++ks) {
    b16x8 ah = ldfrag_sc1(hr + ks * 32);
    b16x8 b0 = *(const b16x8*)(w0 + ks * 32);
    b16x8 b1 = *(const b16x8*)(w1 + ks * 32);
    a0 = __builtin_amdgcn_mfma_f32_16x16x32_bf16(ah, b0, a0, 0, 0, 0);
    a1 = __builtin_amdgcn_mfma_f32_16x16x32_bf16(ah, b1, a1, 0, 0, 0);
  }
#pragma unroll
  for (int ri = 0; ri < 4; ++ri) {
    sS[kh][mf * 16 + gg * 4 + ri][lr] = a0[ri];
    sS[kh][mf * 16 + gg * 4 + ri][16 + lr] = a1[ri];
  }
  __syncthreads();
  // softmax over 32 logits per row
  int r = t >> 3, q = t & 7;
  float4 pre = *(const float4*)(attn_pre + ((size_t)l * BA + r0 + r) * 32 + q * 4);
  float v0 = sS[0][r][q * 4 + 0] + sS[1][r][q * 4 + 0] + pre.x;
  float v1 = sS[0][r][q * 4 + 1] + sS[1][r][q * 4 + 1] + pre.y;
  float v2 = sS[0][r][q * 4 + 2] + sS[1][r][q * 4 + 2] + pre.z;
  float v3 = sS[0][r][q * 4 + 3] + sS[1][r][q * 4 + 3] + pre.w;
  float mx = fmaxf(fmaxf(v0, v1), fmaxf(v2, v3));
  for (int o = 1; o < 8; o <<= 1) mx = fmaxf(mx, __shfl_xor(mx, o, 64));
  float e0 = expf(v0 - mx), e1 = expf(v1 - mx), e2 = expf(v2 - mx), e3 = expf(v3 - mx);
  float s = e0 + e1 + e2 + e3;
  for (int o = 1; o < 8; o <<= 1) s += __shfl_xor(s, o, 64);
  float inv = 1.f / s;
  sAW[r][q * 4 + 0] = e0 * inv; sAW[r][q * 4 + 1] = e1 * inv;
  sAW[r][q * 4 + 2] = e2 * inv; sAW[r][q * 4 + 3] = e3 * inv;
  __syncthreads();
  // apply d-slice: d0 = sl*16, each thread 2 d's (enc_outs static: plain loads)
  int d0 = sl * 16;
  int rr = t >> 3, dp = t & 7;
  int d = d0 + dp * 2;
  float f0 = 0.f, f1 = 0.f;
#pragma unroll 8
  for (int ll = 0; ll < 32; ++ll) {
    float aw = sAW[rr][ll];
    unsigned u = *(const unsigned*)(enc_bf + ((size_t)ll * BA + r0 + rr) * HD + d);
    f0 += aw * __uint_as_float(u << 16);
    f1 += aw * __uint_as_float(u & 0xffff0000u);
  }
  unsigned ov = (unsigned)f2bf(f0) | ((unsigned)f2bf(f1) << 16);
  *(unsigned*)&stile[rr][dp * 2] = ov;
  __syncthreads();
  if (t < 128) {
    int row = t >> 2, c = t & 3;
    st_sc1(applied + (size_t)(r0 + row) * HD + sl * 16 + c * 4,
           *(const unsigned long long*)&stile[row][c * 4]);
  }
}

__global__ __launch_bounds__(256) void coop_k(CoopArgs a) {
  __shared__ float red[2][6][64][4];
  __shared__ float sS[2][32][33];
  __shared__ float sAW[32][33];
  __shared__ ushort stile[32][16];
  int bid = blockIdx.x;
  int rg = bid >> 5, sl = bid & 31;
  int t = threadIdx.x, lane = t & 63, w = t >> 6;
  int r0 = rg * 32;
  unsigned int* ctr = a.ctr + rg * 64;
  int sync_idx = 0;

  auto gsync = [&]() {
    ++sync_idx;
    __syncthreads();   // drains vmcnt(0): all sc1 stores complete at LLC
    if (t == 0) {
      __hip_atomic_fetch_add(ctr, 1u, __ATOMIC_RELEASE, __HIP_MEMORY_SCOPE_AGENT);
      while (__hip_atomic_load(ctr, __ATOMIC_RELAXED, __HIP_MEMORY_SCOPE_AGENT) <
             (unsigned int)(32 * sync_idx))
        __builtin_amdgcn_s_sleep(2);
    }
    __syncthreads();
  };

  float hp[4] = {0.f, 0.f, 0.f, 0.f};

  // ---- encoder: 32 steps ----
  for (int l = 0; l < SL; ++l) {
    gru_phase<false>(r0, sl, lane, w, t,
                     a.enc_emb_bf + (size_t)l * BH,
                     l ? a.enc_outs_bf + (size_t)(l - 1) * BH : nullptr,
                     a.enc_wih, a.enc_whh, a.enc_b_ih, a.enc_b_hh,
                     hp, a.enc_outs_bf + (size_t)l * BH, red, stile);
    gsync();
  }
  // ---- decoder: 32 steps x 3 phases ----
  for (int l = 0; l < SL; ++l) {
    const ushort* h_bf = l ? a.H2_bf + (size_t)(l - 1) * BH
                           : a.enc_outs_bf + (size_t)31 * BH;
    attn_phase(r0, sl, lane, w, t, l, h_bf, a.attn_w_bf, a.attn_pre,
               a.enc_outs_bf, a.applied_bf, sS, sAW, stile);
    gsync();
    comb_phase(r0, sl, lane, w, t, l, a.applied_bf, a.comb_w_bf, a.comb_pre,
               a.x_bf, red, stile);
    gsync();
    gru_phase<true>(r0, sl, lane, w, t, a.x_bf, h_bf,
                    a.dec_wih, a.dec_whh, a.dec_b_ih, a.dec_b_hh,
                    hp, a.H2_bf + (size_t)l * BH, red, stile);
    gsync();
  }
}

// ---------------- log-softmax: pass 1 (per-row logsumexp) ----------------
__global__ __launch_bounds__(256) void lse_k(const float* __restrict__ logits,
                                             float* __restrict__ z) {
  __shared__ float red[4];
  int row = blockIdx.x, t = threadIdx.x;
  const float4* p = (const float4*)(logits + (size_t)row * VOC);
  float m = -1e30f;
  for (int i = t; i < 2500; i += 256) {
    float4 v = p[i];
    m = fmaxf(fmaxf(m, fmaxf(v.x, v.y)), fmaxf(v.z, v.w));
  }
  for (int o = 32; o; o >>= 1) m = fmaxf(m, __shfl_xor(m, o, 64));
  if ((t & 63) == 0) red[t >> 6] = m;
  __syncthreads();
  m = fmaxf(fmaxf(red[0], red[1]), fmaxf(red[2], red[3]));
  __syncthreads();
  float s = 0.f;
  for (int i = t; i < 2500; i += 256) {
    float4 v = p[i];
    s += expf(v.x - m) + expf(v.y - m) + expf(v.z - m) + expf(v.w - m);
  }
  for (int o = 32; o; o >>= 1) s += __shfl_xor(s, o, 64);
  if ((t & 63) == 0) red[t >> 6] = s;
  __syncthreads();
  if (t == 0) z[row] = m + logf(red[0] + red[1] + red[2] + red[3]);
}

// ---------------- log-softmax: pass 2 (subtract) ----------------
__global__ __launch_bounds__(256) void sub_k(float* __restrict__ logits,
                                             const float* __restrict__ z) {
  int row = blockIdx.y;
  int i = blockIdx.x * 256 + threadIdx.x;
  if (i < 2500) {
    float4* p = (float4*)(logits + (size_t)row * VOC);
    float zv = z[row];
    float4 v = p[i];
    v.x -= zv; v.y -= zv; v.z -= zv; v.w -= zv;
    p[i] = v;
  }
}

extern "C" void kernel_launch(void* const* d_in, const int* in_sizes, int n_in,
                              void* d_out, int out_size, void* d_ws, size_t ws_size,
                              hipStream_t stream) {
  (void)in_sizes; (void)n_in; (void)out_size; (void)ws_size;
  const int* in_tok = (const int*)d_in[0];
  const int* tgt_tok = (const int*)d_in[1];
  const float* enc_embed = (const float*)d_in[2];
  const float* enc_w_ih = (const float*)d_in[3];
  const float* enc_w_hh = (const float*)d_in[4];
  const float* enc_b_ih = (const float*)d_in[5];
  const float* enc_b_hh = (const float*)d_in[6];
  const float* dec_embed = (const float*)d_in[7];
  const float* attn_w = (const float*)d_in[8];
  const float* attn_b = (const float*)d_in[9];
  const float* comb_w = (const float*)d_in[10];
  const float* comb_b = (const float*)d_in[11];
  const float* dec_w_ih = (const float*)d_in[12];
  const float* dec_w_hh = (const float*)d_in[13];
  const float* dec_b_ih = (const float*)d_in[14];
  const float* dec_b_hh = (const float*)d_in[15];
  const float* out_w = (const float*)d_in[16];
  const float* out_b = (const float*)d_in[17];
  float* out = (float*)d_out;

  char* ws = (char*)d_ws;
  size_t off = 0;
  auto carve = [&](size_t bytes) {
    void* p = ws + off;
    off += (bytes + 255) & ~(size_t)255;
    return p;
  };
  ushort* enc_wih_bf = (ushort*)carve(1536 * 512 * 2);
  ushort* enc_whh_bf = (ushort*)carve(1536 * 512 * 2);
  ushort* dec_wih_bf = (ushort*)carve(1536 * 512 * 2);
  ushort* dec_whh_bf = (ushort*)carve(1536 * 512 * 2);
  ushort* comb_w_bf  = (ushort*)carve(512 * 1024 * 2);
  ushort* attn_w_bf  = (ushort*)carve(32 * 1024 * 2);
  ushort* out_w_bf   = (ushort*)carve((size_t)VOC * HD * 2);
  ushort* enc_emb_bf = (ushort*)carve((size_t)SL * BA * HD * 2);
  ushort* dec_emb_bf = (ushort*)carve((size_t)SL * BA * HD * 2);
  float* attn_pre    = (float*)carve((size_t)SL * BA * 32 * 4);
  float* comb_pre    = (float*)carve((size_t)SL * BA * HD * 4);
  ushort* enc_outs_bf= (ushort*)carve((size_t)SL * BA * HD * 2);
  ushort* H2_bf      = (ushort*)carve((size_t)SL * BA * HD * 2);
  ushort* applied_bf = (ushort*)carve(BH * 2);
  ushort* x_bf       = (ushort*)carve(BH * 2);
  float* zbuf        = (float*)carve(SL * BA * 4);
  unsigned int* ctr  = (unsigned int*)carve(8 * 64 * 4);

  // ---- setup: converts, gathers, zero counters ----
  cvt_k<<<768, 256, 0, stream>>>(enc_w_ih, enc_wih_bf, 1536 * 512 / 4);
  cvt_k<<<768, 256, 0, stream>>>(enc_w_hh, enc_whh_bf, 1536 * 512 / 4);
  cvt_k<<<768, 256, 0, stream>>>(dec_w_ih, dec_wih_bf, 1536 * 512 / 4);
  cvt_k<<<768, 256, 0, stream>>>(dec_w_hh, dec_whh_bf, 1536 * 512 / 4);
  cvt_k<<<512, 256, 0, stream>>>(comb_w, comb_w_bf, 512 * 1024 / 4);
  cvt_k<<<32, 256, 0, stream>>>(attn_w, attn_w_bf, 32 * 1024 / 4);
  cvt_k<<<5000, 256, 0, stream>>>(out_w, out_w_bf, VOC * HD / 4);
  gather_enc_k<<<SL * BA, 64, 0, stream>>>(enc_embed, in_tok, enc_emb_bf);
  gather_dec_k<<<SL * BA, 64, 0, stream>>>(dec_embed, tgt_tok, dec_emb_bf);
  hipMemsetAsync(ctr, 0, 8 * 64 * 4, stream);

  // ---- decoder embedding-dependent precomputes ----
  gemm_k<<<dim3(128, 1), 256, 0, stream>>>(dec_emb_bf, attn_w_bf, 32, 1024,
                                           attn_b, nullptr, 0, attn_pre, 32, nullptr);
  gemm_k<<<dim3(128, 8), 256, 0, stream>>>(dec_emb_bf, comb_w_bf, 512, 1024,
                                           comb_b, nullptr, 0, comb_pre, 512, nullptr);

  // ---- persistent recurrence ----
  CoopArgs ca;
  ca.enc_emb_bf = enc_emb_bf;
  ca.enc_outs_bf = enc_outs_bf;
  ca.H2_bf = H2_bf;
  ca.x_bf = x_bf;
  ca.applied_bf = applied_bf;
  ca.enc_wih = enc_wih_bf; ca.enc_whh = enc_whh_bf;
  ca.enc_b_ih = enc_b_ih; ca.enc_b_hh = enc_b_hh;
  ca.dec_wih = dec_wih_bf; ca.dec_whh = dec_whh_bf;
  ca.dec_b_ih = dec_b_ih; ca.dec_b_hh = dec_b_hh;
  ca.attn_w_bf = attn_w_bf;
  ca.attn_pre = attn_pre;
  ca.comb_w_bf = comb_w_bf;
  ca.comb_pre = comb_pre;
  ca.ctr = ctr;
  coop_k<<<256, 256, 0, stream>>>(ca);

  // ---- output projection + log_softmax ----
  gemm_k<<<dim3(128, 157), 256, 0, stream>>>(H2_bf, out_w_bf, VOC, HD,
                                             out_b, nullptr, 0, out, VOC, nullptr);
  lse_k<<<SL * BA, 256, 0, stream>>>(out, zbuf);
  sub_k<<<dim3(10, SL * BA), 256, 0, stream>>>(out, zbuf);
}

// Round 4
// 1738.390 us; speedup vs baseline: 3.0106x; 1.2975x over previous
//
#include <hip/hip_runtime.h>

#define HD 512
#define VOC 10000
#define SL 32
#define BA 256
#define BH (BA*HD)

typedef __bf16 b16x8 __attribute__((ext_vector_type(8)));
typedef float f32x4 __attribute__((ext_vector_type(4)));
typedef unsigned u32x4 __attribute__((ext_vector_type(4)));

__device__ __forceinline__ ushort f2bf(float x) {
  unsigned u = __float_as_uint(x);
  u += 0x7fffu + ((u >> 16) & 1u);
  return (ushort)(u >> 16);
}

// ---- LLC-coherent wide accessors (bypass L1/L2, no cache invalidation) ----
__device__ __forceinline__ b16x8 ldg_sc(const void* p) {
  u32x4 r;
  asm volatile("global_load_dwordx4 %0, %1, off sc0 sc1"
               : "=v"(r) : "v"(p) : "memory");
  return __builtin_bit_cast(b16x8, r);
}
__device__ __forceinline__ void stg_sc(void* p, u32x4 v) {
  asm volatile("global_store_dwordx4 %0, %1, off sc0 sc1"
               :: "v"(p), "v"(v) : "memory");
}
__device__ __forceinline__ void vmwait0() {
  asm volatile("s_waitcnt vmcnt(0)" ::: "memory");
  __builtin_amdgcn_sched_barrier(0);   // rule #18: pin MFMAs after the wait
}

// ---------------- fp32 -> bf16 convert ----------------
__global__ __launch_bounds__(256) void cvt_k(const float* __restrict__ in,
                                             ushort* __restrict__ out, int n4) {
  int i = blockIdx.x * 256 + threadIdx.x;
  if (i < n4) {
    float4 v = ((const float4*)in)[i];
    ((ushort4*)out)[i] = make_ushort4(f2bf(v.x), f2bf(v.y), f2bf(v.z), f2bf(v.w));
  }
}

// ---------------- embedding gathers (rows = l*256+b) ----------------
__global__ __launch_bounds__(64) void gather_enc_k(const float* __restrict__ table,
                                                   const int* __restrict__ toks,
                                                   ushort* __restrict__ out) {
  int row = blockIdx.x;            // l*256 + b
  int l = row >> 8, b = row & 255;
  int tok = toks[b * SL + l];
  const float4* src = (const float4*)(table + (size_t)tok * HD);
  int t = threadIdx.x;
  float4 v0 = src[t * 2], v1 = src[t * 2 + 1];
  uint4 o;
  o.x = (unsigned)f2bf(v0.x) | ((unsigned)f2bf(v0.y) << 16);
  o.y = (unsigned)f2bf(v0.z) | ((unsigned)f2bf(v0.w) << 16);
  o.z = (unsigned)f2bf(v1.x) | ((unsigned)f2bf(v1.y) << 16);
  o.w = (unsigned)f2bf(v1.z) | ((unsigned)f2bf(v1.w) << 16);
  *(uint4*)(out + (size_t)row * HD + t * 8) = o;
}

__global__ __launch_bounds__(64) void gather_dec_k(const float* __restrict__ table,
                                                   const int* __restrict__ toks,
                                                   ushort* __restrict__ out) {
  int row = blockIdx.x;
  int l = row >> 8, b = row & 255;
  int tok = (l == 0) ? 1 : toks[b * SL + l - 1];
  const float4* src = (const float4*)(table + (size_t)tok * HD);
  int t = threadIdx.x;
  float4 v0 = src[t * 2], v1 = src[t * 2 + 1];
  uint4 o;
  o.x = (unsigned)f2bf(v0.x) | ((unsigned)f2bf(v0.y) << 16);
  o.y = (unsigned)f2bf(v0.z) | ((unsigned)f2bf(v0.w) << 16);
  o.z = (unsigned)f2bf(v1.x) | ((unsigned)f2bf(v1.y) << 16);
  o.w = (unsigned)f2bf(v1.z) | ((unsigned)f2bf(v1.w) << 16);
  *(uint4*)(out + (size_t)row * HD + t * 8) = o;
}

// ---------------- generic bf16 GEMM: C[m][n] = sum_k A[m][k]*W[n][k] ----------------
__global__ __launch_bounds__(256) void gemm_k(
    const ushort* __restrict__ A, const ushort* __restrict__ W,
    int N, int ldw,
    const float* __restrict__ bias, const float* __restrict__ addsrc,
    int relu, float* __restrict__ outf, int ldc, ushort* __restrict__ outbf) {
  __shared__ ushort lsA[4][64][8];
  __shared__ ushort lsB[4][64][8];
  int t = threadIdx.x;
  int lane = t & 63, w = t >> 6;
  int m0 = blockIdx.x * 64, n0 = blockIdx.y * 64;
  f32x4 acc[4] = {};
  int sr = t >> 2, g = t & 3;
  const ushort* Ap = A + (size_t)(m0 + sr) * HD + g * 8;
  int nr = n0 + sr; if (nr > N - 1) nr = N - 1;
  const ushort* Wp = W + (size_t)nr * ldw + g * 8;
  for (int ks = 0; ks < 16; ++ks) {
    *(uint4*)(&lsA[g][sr][0]) = *(const uint4*)(Ap + ks * 32);
    *(uint4*)(&lsB[g][sr][0]) = *(const uint4*)(Wp + ks * 32);
    __syncthreads();
    int gg = lane >> 4, r = lane & 15;
    b16x8 bf = *(const b16x8*)(&lsB[gg][w * 16 + r][0]);
#pragma unroll
    for (int mi = 0; mi < 4; ++mi) {
      b16x8 af = *(const b16x8*)(&lsA[gg][mi * 16 + r][0]);
      acc[mi] = __builtin_amdgcn_mfma_f32_16x16x32_bf16(af, bf, acc[mi], 0, 0, 0);
    }
    __syncthreads();
  }
  int gg = lane >> 4, cl = lane & 15;
  int col = n0 + w * 16 + cl;
  if (col >= N) return;
  float bv = bias ? bias[col] : 0.f;
#pragma unroll
  for (int mi = 0; mi < 4; ++mi) {
#pragma unroll
    for (int r = 0; r < 4; ++r) {
      int row = m0 + mi * 16 + gg * 4 + r;
      float v = acc[mi][r] + bv;
      if (addsrc) v += addsrc[(size_t)row * N + col];
      if (relu) v = fmaxf(v, 0.f);
      if (outf) outf[(size_t)row * ldc + col] = v;
      if (outbf) outbf[(size_t)row * N + col] = f2bf(v);
    }
  }
}

// ---------------- persistent recurrence kernel ----------------
// 256 blocks x 256 threads. rg = bid & 7 (XCD-clustered under round-robin
// dispatch), sl = bid >> 3. Each rg owns 32 batch rows; 32 blocks per rg.
// Weights/precomputes: plain cached loads (L2-hot, never invalidated).
// Dynamic activations: sc0sc1 wide loads/stores straight at LLC, batched,
// one vmcnt wait per phase.

struct CoopArgs {
  const ushort* enc_emb_bf;
  ushort* enc_outs_bf;       // [SL][BA][HD]
  ushort* H2_bf;             // [SL][BA][HD]
  ushort* x_bf;              // [BA][HD]
  ushort* applied_bf;        // [BA][HD]
  const ushort* enc_wih; const ushort* enc_whh;
  const float* enc_b_ih; const float* enc_b_hh;
  const ushort* dec_wih; const ushort* dec_whh;
  const float* dec_b_ih; const float* dec_b_hh;
  const ushort* attn_w_bf;   // [32][1024] (right half used)
  const float* attn_pre;     // [SL*BA][32]
  const ushort* comb_w_bf;   // [512][1024] (right half used)
  const float* comb_pre;     // [SL*BA][512]
  unsigned int* ctr;         // 8 counters, stride 64 uints
};

template <bool XFRESH>
__device__ __forceinline__ void gru_phase(
    int r0, int sl, int lane, int w, int t,
    const ushort* __restrict__ x_src, const ushort* __restrict__ h_src,
    const ushort* __restrict__ Wih, const ushort* __restrict__ Whh,
    const float* __restrict__ b_ih, const float* __restrict__ b_hh,
    float* hp, ushort* __restrict__ hbf_dst,
    float (*red)[6][64][4], ushort (*stile)[16]) {
  int mf = w & 1, kh = w >> 1;
  int lr = lane & 15, gg = lane >> 4;
  int row_a = r0 + mf * 16 + lr;
  int jrow = sl * 16 + lr;
  const ushort* xr = x_src + (size_t)row_a * HD + kh * 256 + gg * 8;
  const ushort* hr = h_src ? h_src + (size_t)row_a * HD + kh * 256 + gg * 8 : nullptr;
  const ushort* wi = Wih + (size_t)jrow * HD + kh * 256 + gg * 8;
  const ushort* wh = Whh + (size_t)jrow * HD + kh * 256 + gg * 8;
  b16x8 xa[8], ha[8];
#pragma unroll
  for (int ks = 0; ks < 8; ++ks)
    xa[ks] = XFRESH ? ldg_sc(xr + ks * 32) : *(const b16x8*)(xr + ks * 32);
  if (hr) {
#pragma unroll
    for (int ks = 0; ks < 8; ++ks) ha[ks] = ldg_sc(hr + ks * 32);
  } else {
#pragma unroll
    for (int ks = 0; ks < 8; ++ks) ha[ks] = b16x8{};
  }
  vmwait0();
  f32x4 acc[6] = {};
#pragma unroll
  for (int ks = 0; ks < 8; ++ks) {
#pragma unroll
    for (int g3 = 0; g3 < 3; ++g3) {
      b16x8 bi = *(const b16x8*)(wi + (size_t)g3 * 512 * HD + ks * 32);
      b16x8 bh = *(const b16x8*)(wh + (size_t)g3 * 512 * HD + ks * 32);
      acc[g3] = __builtin_amdgcn_mfma_f32_16x16x32_bf16(xa[ks], bi, acc[g3], 0, 0, 0);
      acc[3 + g3] = __builtin_amdgcn_mfma_f32_16x16x32_bf16(ha[ks], bh, acc[3 + g3], 0, 0, 0);
    }
  }
  if (kh == 1) {
#pragma unroll
    for (int s = 0; s < 6; ++s) *(f32x4*)&red[mf][s][lane][0] = acc[s];
  }
  __syncthreads();
  if (kh == 0) {
    int j = sl * 16 + lr;
#pragma unroll
    for (int s = 0; s < 6; ++s) acc[s] += *(const f32x4*)&red[mf][s][lane][0];
    float bir = b_ih[j], biz = b_ih[512 + j], bin_ = b_ih[1024 + j];
    float bhr = b_hh[j], bhz = b_hh[512 + j], bhn = b_hh[1024 + j];
#pragma unroll
    for (int ri = 0; ri < 4; ++ri) {
      float ir = acc[0][ri] + bir, iz = acc[1][ri] + biz, inn = acc[2][ri] + bin_;
      float hr2 = acc[3][ri] + bhr, hz = acc[4][ri] + bhz, hn = acc[5][ri] + bhn;
      float rr = 1.f / (1.f + expf(-(ir + hr2)));
      float zz = 1.f / (1.f + expf(-(iz + hz)));
      float nn = tanhf(inn + rr * hn);
      float h2 = (1.f - zz) * nn + zz * hp[ri];
      hp[ri] = h2;
      stile[mf * 16 + gg * 4 + ri][lr] = f2bf(h2);
    }
  }
  __syncthreads();
  if (t < 64) {
    int row = t >> 1, c = t & 1;
    stg_sc(hbf_dst + (size_t)(r0 + row) * HD + sl * 16 + c * 8,
           *(const u32x4*)&stile[row][c * 8]);
    vmwait0();
  }
}

__device__ __forceinline__ void comb_phase(
    int r0, int sl, int lane, int w, int t, int l,
    const ushort* __restrict__ applied, const ushort* __restrict__ comb_w_bf,
    const float* __restrict__ comb_pre, ushort* __restrict__ x_bf,
    float (*red)[6][64][4], ushort (*stile)[16]) {
  int mf = w & 1, kh = w >> 1;
  int lr = lane & 15, gg = lane >> 4;
  int row_a = r0 + mf * 16 + lr;
  int nrow = sl * 16 + lr;
  const ushort* ar = applied + (size_t)row_a * HD + kh * 256 + gg * 8;
  const ushort* wr = comb_w_bf + (size_t)nrow * 1024 + 512 + kh * 256 + gg * 8;
  b16x8 av[8];
#pragma unroll
  for (int ks = 0; ks < 8; ++ks) av[ks] = ldg_sc(ar + ks * 32);
  vmwait0();
  f32x4 acc = {};
#pragma unroll
  for (int ks = 0; ks < 8; ++ks) {
    b16x8 bv = *(const b16x8*)(wr + ks * 32);
    acc = __builtin_amdgcn_mfma_f32_16x16x32_bf16(av[ks], bv, acc, 0, 0, 0);
  }
  if (kh == 1) *(f32x4*)&red[mf][0][lane][0] = acc;
  __syncthreads();
  if (kh == 0) {
    acc += *(const f32x4*)&red[mf][0][lane][0];
    int n = sl * 16 + lr;
#pragma unroll
    for (int ri = 0; ri < 4; ++ri) {
      int row = r0 + mf * 16 + gg * 4 + ri;
      float v = acc[ri] + comb_pre[((size_t)l * BA + row) * HD + n];
      v = fmaxf(v, 0.f);
      stile[mf * 16 + gg * 4 + ri][lr] = f2bf(v);
    }
  }
  __syncthreads();
  if (t < 64) {
    int row = t >> 1, c = t & 1;
    stg_sc(x_bf + (size_t)(r0 + row) * HD + sl * 16 + c * 8,
           *(const u32x4*)&stile[row][c * 8]);
    vmwait0();
  }
}

__device__ __forceinline__ void attn_phase(
    int r0, int sl, int lane, int w, int t, int l,
    const ushort* __restrict__ h_bf, const ushort* __restrict__ attn_w_bf,
    const float* __restrict__ attn_pre, const ushort* __restrict__ enc_bf,
    ushort* __restrict__ applied,
    float (*sS)[32][33], float (*sAW)[33], ushort (*stile)[16]) {
  int mf = w & 1, kh = w >> 1;
  int lr = lane & 15, gg = lane >> 4;
  int row_a = r0 + mf * 16 + lr;
  const ushort* hr = h_bf + (size_t)row_a * HD + kh * 256 + gg * 8;
  const ushort* w0 = attn_w_bf + (size_t)lr * 1024 + 512 + kh * 256 + gg * 8;
  const ushort* w1 = attn_w_bf + (size_t)(16 + lr) * 1024 + 512 + kh * 256 + gg * 8;
  b16x8 hfrag[8];
#pragma unroll
  for (int ks = 0; ks < 8; ++ks) hfrag[ks] = ldg_sc(hr + ks * 32);
  vmwait0();
  f32x4 a0 = {}, a1 = {};
#pragma unroll
  for (int ks = 0; ks < 8; ++ks) {
    b16x8 b0 = *(const b16x8*)(w0 + ks * 32);
    b16x8 b1 = *(const b16x8*)(w1 + ks * 32);
    a0 = __builtin_amdgcn_mfma_f32_16x16x32_bf16(hfrag[ks], b0, a0, 0, 0, 0);
    a1 = __builtin_amdgcn_mfma_f32_16x16x32_bf16(hfrag[ks], b1, a1, 0, 0, 0);
  }
#pragma unroll
  for (int ri = 0; ri < 4; ++ri) {
    sS[kh][mf * 16 + gg * 4 + ri][lr] = a0[ri];
    sS[kh][mf * 16 + gg * 4 + ri][16 + lr] = a1[ri];
  }
  __syncthreads();
  // softmax over 32 logits per row
  int r = t >> 3, q = t & 7;
  float4 pre = *(const float4*)(attn_pre + ((size_t)l * BA + r0 + r) * 32 + q * 4);
  float v0 = sS[0][r][q * 4 + 0] + sS[1][r][q * 4 + 0] + pre.x;
  float v1 = sS[0][r][q * 4 + 1] + sS[1][r][q * 4 + 1] + pre.y;
  float v2 = sS[0][r][q * 4 + 2] + sS[1][r][q * 4 + 2] + pre.z;
  float v3 = sS[0][r][q * 4 + 3] + sS[1][r][q * 4 + 3] + pre.w;
  float mx = fmaxf(fmaxf(v0, v1), fmaxf(v2, v3));
  for (int o = 1; o < 8; o <<= 1) mx = fmaxf(mx, __shfl_xor(mx, o, 64));
  float e0 = expf(v0 - mx), e1 = expf(v1 - mx), e2 = expf(v2 - mx), e3 = expf(v3 - mx);
  float s = e0 + e1 + e2 + e3;
  for (int o = 1; o < 8; o <<= 1) s += __shfl_xor(s, o, 64);
  float inv = 1.f / s;
  sAW[r][q * 4 + 0] = e0 * inv; sAW[r][q * 4 + 1] = e1 * inv;
  sAW[r][q * 4 + 2] = e2 * inv; sAW[r][q * 4 + 3] = e3 * inv;
  __syncthreads();
  // apply d-slice: d0 = sl*16, each thread 2 d's (enc_outs static: cached loads)
  int d0 = sl * 16;
  int rr = t >> 3, dp = t & 7;
  int d = d0 + dp * 2;
  float f0 = 0.f, f1 = 0.f;
#pragma unroll 8
  for (int ll = 0; ll < 32; ++ll) {
    float aw = sAW[rr][ll];
    unsigned u = *(const unsigned*)(enc_bf + ((size_t)ll * BA + r0 + rr) * HD + d);
    f0 += aw * __uint_as_float(u << 16);
    f1 += aw * __uint_as_float(u & 0xffff0000u);
  }
  unsigned ov = (unsigned)f2bf(f0) | ((unsigned)f2bf(f1) << 16);
  *(unsigned*)&stile[rr][dp * 2] = ov;
  __syncthreads();
  if (t < 64) {
    int row = t >> 1, c = t & 1;
    stg_sc(applied + (size_t)(r0 + row) * HD + sl * 16 + c * 8,
           *(const u32x4*)&stile[row][c * 8]);
    vmwait0();
  }
}

__global__ __launch_bounds__(256) void coop_k(CoopArgs a) {
  __shared__ float red[2][6][64][4];
  __shared__ float sS[2][32][33];
  __shared__ float sAW[32][33];
  __shared__ ushort stile[32][16];
  int bid = blockIdx.x;
  int rg = bid & 7, sl = bid >> 3;     // rg clustered per XCD (round-robin)
  int t = threadIdx.x, lane = t & 63, w = t >> 6;
  int r0 = rg * 32;
  unsigned int* ctr = a.ctr + rg * 64;
  int sync_idx = 0;

  auto gsync = [&]() {
    ++sync_idx;
    __syncthreads();   // all lanes' sc stores already drained (vmwait0)
    if (t == 0) {
      __hip_atomic_fetch_add(ctr, 1u, __ATOMIC_RELEASE, __HIP_MEMORY_SCOPE_AGENT);
      while (__hip_atomic_load(ctr, __ATOMIC_RELAXED, __HIP_MEMORY_SCOPE_AGENT) <
             (unsigned int)(32 * sync_idx))
        __builtin_amdgcn_s_sleep(1);
    }
    __syncthreads();
  };

  float hp[4] = {0.f, 0.f, 0.f, 0.f};

  // ---- encoder: 32 steps ----
  for (int l = 0; l < SL; ++l) {
    gru_phase<false>(r0, sl, lane, w, t,
                     a.enc_emb_bf + (size_t)l * BH,
                     l ? a.enc_outs_bf + (size_t)(l - 1) * BH : nullptr,
                     a.enc_wih, a.enc_whh, a.enc_b_ih, a.enc_b_hh,
                     hp, a.enc_outs_bf + (size_t)l * BH, red, stile);
    gsync();
  }
  // ---- decoder: 32 steps x 3 phases ----
  for (int l = 0; l < SL; ++l) {
    const ushort* h_bf = l ? a.H2_bf + (size_t)(l - 1) * BH
                           : a.enc_outs_bf + (size_t)31 * BH;
    attn_phase(r0, sl, lane, w, t, l, h_bf, a.attn_w_bf, a.attn_pre,
               a.enc_outs_bf, a.applied_bf, sS, sAW, stile);
    gsync();
    comb_phase(r0, sl, lane, w, t, l, a.applied_bf, a.comb_w_bf, a.comb_pre,
               a.x_bf, red, stile);
    gsync();
    gru_phase<true>(r0, sl, lane, w, t, a.x_bf, h_bf,
                    a.dec_wih, a.dec_whh, a.dec_b_ih, a.dec_b_hh,
                    hp, a.H2_bf + (size_t)l * BH, red, stile);
    gsync();
  }
}

// ---------------- fused log-softmax: z then subtract, one kernel ----------------
__global__ __launch_bounds__(256) void lsesub_k(float* __restrict__ logits) {
  __shared__ float red[4];
  __shared__ float zsh;
  int row = blockIdx.x, t = threadIdx.x;
  float4* p = (float4*)(logits + (size_t)row * VOC);
  float m = -1e30f;
  for (int i = t; i < 2500; i += 256) {
    float4 v = p[i];
    m = fmaxf(fmaxf(m, fmaxf(v.x, v.y)), fmaxf(v.z, v.w));
  }
  for (int o = 32; o; o >>= 1) m = fmaxf(m, __shfl_xor(m, o, 64));
  if ((t & 63) == 0) red[t >> 6] = m;
  __syncthreads();
  m = fmaxf(fmaxf(red[0], red[1]), fmaxf(red[2], red[3]));
  __syncthreads();
  float s = 0.f;
  for (int i = t; i < 2500; i += 256) {
    float4 v = p[i];
    s += expf(v.x - m) + expf(v.y - m) + expf(v.z - m) + expf(v.w - m);
  }
  for (int o = 32; o; o >>= 1) s += __shfl_xor(s, o, 64);
  if ((t & 63) == 0) red[t >> 6] = s;
  __syncthreads();
  if (t == 0) zsh = m + logf(red[0] + red[1] + red[2] + red[3]);
  __syncthreads();
  float z = zsh;
  for (int i = t; i < 2500; i += 256) {
    float4 v = p[i];
    v.x -= z; v.y -= z; v.z -= z; v.w -= z;
    p[i] = v;
  }
}

extern "C" void kernel_launch(void* const* d_in, const int* in_sizes, int n_in,
                              void* d_out, int out_size, void* d_ws, size_t ws_size,
                              hipStream_t stream) {
  (void)in_sizes; (void)n_in; (void)out_size; (void)ws_size;
  const int* in_tok = (const int*)d_in[0];
  const int* tgt_tok = (const int*)d_in[1];
  const float* enc_embed = (const float*)d_in[2];
  const float* enc_w_ih = (const float*)d_in[3];
  const float* enc_w_hh = (const float*)d_in[4];
  const float* enc_b_ih = (const float*)d_in[5];
  const float* enc_b_hh = (const float*)d_in[6];
  const float* dec_embed = (const float*)d_in[7];
  const float* attn_w = (const float*)d_in[8];
  const float* attn_b = (const float*)d_in[9];
  const float* comb_w = (const float*)d_in[10];
  const float* comb_b = (const float*)d_in[11];
  const float* dec_w_ih = (const float*)d_in[12];
  const float* dec_w_hh = (const float*)d_in[13];
  const float* dec_b_ih = (const float*)d_in[14];
  const float* dec_b_hh = (const float*)d_in[15];
  const float* out_w = (const float*)d_in[16];
  const float* out_b = (const float*)d_in[17];
  float* out = (float*)d_out;

  char* ws = (char*)d_ws;
  size_t off = 0;
  auto carve = [&](size_t bytes) {
    void* p = ws + off;
    off += (bytes + 255) & ~(size_t)255;
    return p;
  };
  ushort* enc_wih_bf = (ushort*)carve(1536 * 512 * 2);
  ushort* enc_whh_bf = (ushort*)carve(1536 * 512 * 2);
  ushort* dec_wih_bf = (ushort*)carve(1536 * 512 * 2);
  ushort* dec_whh_bf = (ushort*)carve(1536 * 512 * 2);
  ushort* comb_w_bf  = (ushort*)carve(512 * 1024 * 2);
  ushort* attn_w_bf  = (ushort*)carve(32 * 1024 * 2);
  ushort* out_w_bf   = (ushort*)carve((size_t)VOC * HD * 2);
  ushort* enc_emb_bf = (ushort*)carve((size_t)SL * BA * HD * 2);
  ushort* dec_emb_bf = (ushort*)carve((size_t)SL * BA * HD * 2);
  float* attn_pre    = (float*)carve((size_t)SL * BA * 32 * 4);
  float* comb_pre    = (float*)carve((size_t)SL * BA * HD * 4);
  ushort* enc_outs_bf= (ushort*)carve((size_t)SL * BA * HD * 2);
  ushort* H2_bf      = (ushort*)carve((size_t)SL * BA * HD * 2);
  ushort* applied_bf = (ushort*)carve(BH * 2);
  ushort* x_bf       = (ushort*)carve(BH * 2);
  unsigned int* ctr  = (unsigned int*)carve(8 * 64 * 4);

  // ---- setup: converts, gathers, zero counters ----
  cvt_k<<<768, 256, 0, stream>>>(enc_w_ih, enc_wih_bf, 1536 * 512 / 4);
  cvt_k<<<768, 256, 0, stream>>>(enc_w_hh, enc_whh_bf, 1536 * 512 / 4);
  cvt_k<<<768, 256, 0, stream>>>(dec_w_ih, dec_wih_bf, 1536 * 512 / 4);
  cvt_k<<<768, 256, 0, stream>>>(dec_w_hh, dec_whh_bf, 1536 * 512 / 4);
  cvt_k<<<512, 256, 0, stream>>>(comb_w, comb_w_bf, 512 * 1024 / 4);
  cvt_k<<<32, 256, 0, stream>>>(attn_w, attn_w_bf, 32 * 1024 / 4);
  cvt_k<<<5000, 256, 0, stream>>>(out_w, out_w_bf, VOC * HD / 4);
  gather_enc_k<<<SL * BA, 64, 0, stream>>>(enc_embed, in_tok, enc_emb_bf);
  gather_dec_k<<<SL * BA, 64, 0, stream>>>(dec_embed, tgt_tok, dec_emb_bf);
  hipMemsetAsync(ctr, 0, 8 * 64 * 4, stream);

  // ---- decoder embedding-dependent precomputes ----
  gemm_k<<<dim3(128, 1), 256, 0, stream>>>(dec_emb_bf, attn_w_bf, 32, 1024,
                                           attn_b, nullptr, 0, attn_pre, 32, nullptr);
  gemm_k<<<dim3(128, 8), 256, 0, stream>>>(dec_emb_bf, comb_w_bf, 512, 1024,
                                           comb_b, nullptr, 0, comb_pre, 512, nullptr);

  // ---- persistent recurrence ----
  CoopArgs ca;
  ca.enc_emb_bf = enc_emb_bf;
  ca.enc_outs_bf = enc_outs_bf;
  ca.H2_bf = H2_bf;
  ca.x_bf = x_bf;
  ca.applied_bf = applied_bf;
  ca.enc_wih = enc_wih_bf; ca.enc_whh = enc_whh_bf;
  ca.enc_b_ih = enc_b_ih; ca.enc_b_hh = enc_b_hh;
  ca.dec_wih = dec_wih_bf; ca.dec_whh = dec_whh_bf;
  ca.dec_b_ih = dec_b_ih; ca.dec_b_hh = dec_b_hh;
  ca.attn_w_bf = attn_w_bf;
  ca.attn_pre = attn_pre;
  ca.comb_w_bf = comb_w_bf;
  ca.comb_pre = comb_pre;
  ca.ctr = ctr;
  coop_k<<<256, 256, 0, stream>>>(ca);

  // ---- output projection + fused log_softmax ----
  gemm_k<<<dim3(128, 157), 256, 0, stream>>>(H2_bf, out_w_bf, VOC, HD,
                                             out_b, nullptr, 0, out, VOC, nullptr);
  lsesub_k<<<SL * BA, 256, 0, stream>>>(out);
}